// Round 10
// baseline (327.829 us; speedup 1.0000x reference)
//
#include <hip/hip_runtime.h>
#include <hip/hip_bf16.h>
#include <stdint.h>

#define T_TOK 32768
#define NEXP 8
#define MROWS 64            // slab rows per block
#define MT64_MAX 520        // 64-row granules incl. per-expert padding (pad=64)
#define MCAP (MT64_MAX * 64)
#define RBLK 512            // routing block threads
#define NBLK (T_TOK / RBLK) // routing blocks = 64
#define SLOTS 128           // slab slots per expert (8192 tokens; >50 sigma)

typedef short s16x8 __attribute__((ext_vector_type(8)));
typedef float f32x4 __attribute__((ext_vector_type(4)));

__device__ __forceinline__ void gload_lds16(const void* g, void* l) {
  typedef const __attribute__((address_space(1))) unsigned int gu32;
  typedef __attribute__((address_space(3))) unsigned int lu32;
  __builtin_amdgcn_global_load_lds((gu32*)(unsigned long long)g,
                                   (lu32*)(unsigned int)(unsigned long long)l,
                                   16, 0, 0);
}

__device__ __forceinline__ unsigned short bf16bits(float v) {
  __hip_bfloat16 h = __float2bfloat16(v);
  return *(unsigned short*)&h;
}

// ---------------- routing (atomic-free at device scope) ----------------

__global__ void k_init(int* __restrict__ perm) {
  int i = blockIdx.x * blockDim.x + threadIdx.x;
  if (i < MCAP) perm[i] = -1;
}

__global__ void k_hist(const float* __restrict__ in, int* __restrict__ ids,
                       int* __restrict__ blockHist) {
  __shared__ int h[NEXP];
  int tid = threadIdx.x;
  if (tid < NEXP) h[tid] = 0;
  __syncthreads();
  int t = blockIdx.x * RBLK + tid;
  const float* p = in + (size_t)t * 136 + 128;
  float bv = p[0]; int best = 0;
#pragma unroll
  for (int j = 1; j < 8; ++j) { float v = p[j]; if (v > bv) { bv = v; best = j; } }
  ids[t] = best;
  atomicAdd(&h[best], 1);   // LDS atomic — cheap
  __syncthreads();
  if (tid < NEXP) blockHist[blockIdx.x * NEXP + tid] = h[tid];
}

// single block: per-expert exclusive prefix over blocks + 64-padded expert offsets
__global__ void k_scan(const int* __restrict__ blockHist, int* __restrict__ blockBase,
                       int* __restrict__ meta) {
  __shared__ int cnt[NEXP];
  int e = threadIdx.x;
  if (e < NEXP) {
    int acc = 0;
    for (int b = 0; b < NBLK; ++b) {
      blockBase[b * NEXP + e] = acc;
      acc += blockHist[b * NEXP + e];
    }
    cnt[e] = acc;
  }
  __syncthreads();
  if (e == 0) {
    int acc = 0;
    for (int i = 0; i < NEXP; ++i) {
      meta[16 + i] = acc;
      acc += ((cnt[i] + 63) / 64) * 64;   // pad to 64-row slabs
    }
    meta[16 + NEXP] = acc;
  }
  __syncthreads();
  if (e < NEXP) {
    int o = meta[16 + e];
    for (int b = 0; b < NBLK; ++b) blockBase[b * NEXP + e] += o;
  }
}

__global__ void k_assign(const int* __restrict__ ids, const int* __restrict__ blockBase,
                         int* __restrict__ rowOf, int* __restrict__ perm) {
  __shared__ int cur[NEXP];
  int tid = threadIdx.x;
  if (tid < NEXP) cur[tid] = blockBase[blockIdx.x * NEXP + tid];
  __syncthreads();
  int t = blockIdx.x * RBLK + tid;
  int e = ids[t];
  int row = atomicAdd(&cur[e], 1);   // LDS atomic — cheap
  rowOf[t] = row;
  perm[row] = t;
}

__global__ void k_gather(const float* __restrict__ in, const int* __restrict__ rowOf,
                         __hip_bfloat16* __restrict__ Xs) {
  int g = blockIdx.x * blockDim.x + threadIdx.x;
  if (g >= T_TOK * 32) return;
  int t = g >> 5, c = g & 31;
  int row = rowOf[t];
  f32x4 v = *(const f32x4*)(in + (size_t)t * 136 + c * 4);
  union { unsigned short u[4]; unsigned long long ll; } pk;
#pragma unroll
  for (int j = 0; j < 4; ++j) pk.u[j] = bf16bits(v[j]);
  *(unsigned long long*)(Xs + (size_t)row * 128 + c * 4) = pk.ll;
}

__global__ void k_padfill(const int* __restrict__ meta, const int* __restrict__ perm,
                          unsigned int* __restrict__ Xs32) {
  int row = blockIdx.x * blockDim.x + threadIdx.x;
  if (row >= MCAP) return;
  int mtotal = meta[16 + NEXP];
  if (row < mtotal && perm[row] < 0) {
    unsigned int* p = Xs32 + (size_t)row * 64;
#pragma unroll 4
    for (int c = 0; c < 64; ++c) p[c] = 0;
  }
}

__global__ void k_w2bf(const float* __restrict__ s, unsigned long long* __restrict__ d, int n4) {
  int i = blockIdx.x * blockDim.x + threadIdx.x;
  if (i >= n4) return;
  f32x4 v = ((const f32x4*)s)[i];
  union { unsigned short u[4]; unsigned long long ll; } pk;
#pragma unroll
  for (int j = 0; j < 4; ++j) pk.u[j] = bf16bits(v[j]);
  d[i] = pk.ll;
}

// ---------------- fused persistent MLP (ping-pong LDS, spill-free passes) ----
// Block = 512 threads (8 waves) owns a 64-token slab for ALL 7 layers.
// TWO 64 KB LDS activation buffers ping-pong. Each layer: per wave, TWO
// sequential 32-col passes (acc f32x4[4][2]=32 regs + W-dbuf 32 + A-frags 16
// -> ~100 live regs, UNDER the toolchain's hard 128-VGPR cap for 8-wave
// blocks that r6-r9 kept hitting and spilling against). Each pass writes its
// columns straight to the out-buffer (no cross-barrier register state), ONE
// barrier per layer. XOR chunk-swizzle on LDS activations. W[e] streams
// global->VGPR from XCD-local L2 (bid&7 = e -> XCD affinity).

template <int KL, int NL, bool RELU>
__device__ __forceinline__ void run_layer(
    const __hip_bfloat16* __restrict__ Wl,   // expert's W base, layout [NL][KL]
    const float* __restrict__ bl,            // expert's bias base
    const __hip_bfloat16* __restrict__ inb,  // [64][KL] swizzled
    __hip_bfloat16* __restrict__ outb,       // [64][NL] swizzled
    int lane, int wave) {
  constexpr int NS = KL / 64;                // K-steps
  constexpr int NPASS = NL / 256;            // 2 (NL=512) or 1 (NL=256)

#pragma unroll
  for (int p = 0; p < NPASS; ++p) {
    const int n0p = wave * (NL / 8) + p * 32;

    f32x4 acc[4][2];
#pragma unroll
    for (int i = 0; i < 4; ++i)
#pragma unroll
      for (int j = 0; j < 2; ++j) {
        acc[i][j][0] = 0.f; acc[i][j][1] = 0.f; acc[i][j][2] = 0.f; acc[i][j][3] = 0.f;
      }

    const __hip_bfloat16* wbase =
        Wl + (size_t)(n0p + (lane & 15)) * KL + ((lane >> 4) << 3);

    s16x8 wA[2][2], wB[2][2];
#pragma unroll
    for (int j = 0; j < 2; ++j)
#pragma unroll
      for (int h = 0; h < 2; ++h)
        wA[j][h] = *(const s16x8*)(wbase + j * 16 * KL + h * 32);

    auto step = [&](int s, s16x8 (&wu)[2][2], s16x8 (&wp)[2][2]) {
      if (s + 1 < NS) {        // prefetch next K-step's W before the MFMAs
#pragma unroll
        for (int j = 0; j < 2; ++j)
#pragma unroll
          for (int h = 0; h < 2; ++h)
            wp[j][h] = *(const s16x8*)(wbase + j * 16 * KL + (s + 1) * 64 + h * 32);
      }
#pragma unroll
      for (int h = 0; h < 2; ++h) {
        int cj = s * 8 + h * 4 + (lane >> 4);  // 16B chunk index within row
#pragma unroll
        for (int i = 0; i < 4; ++i) {
          int ar = i * 16 + (lane & 15);
          int js = cj ^ (ar & 7);
          s16x8 a = *(const s16x8*)(inb + ar * KL + js * 8);
#pragma unroll
          for (int j = 0; j < 2; ++j)
            acc[i][j] = __builtin_amdgcn_mfma_f32_16x16x32_bf16(a, wu[j][h], acc[i][j], 0, 0, 0);
        }
      }
    };

#pragma unroll
    for (int s = 0; s < NS; s += 2) {
      step(s, wA, wB);
      step(s + 1, wB, wA);
    }

    // epilogue: bias + relu, write straight to outb (different LDS buffer)
    unsigned short* y16 = (unsigned short*)outb;
#pragma unroll
    for (int j = 0; j < 2; ++j) {
      int nc = n0p + j * 16 + (lane & 15);
      float bv = bl[nc];
#pragma unroll
      for (int i = 0; i < 4; ++i) {
#pragma unroll
        for (int r = 0; r < 4; ++r) {
          int mr = i * 16 + ((lane >> 4) << 2) + r;
          float v = acc[i][j][r] + bv;
          if (RELU) v = fmaxf(v, 0.f);
          y16[mr * NL + (((nc >> 3) ^ (mr & 7)) << 3) + (nc & 7)] = bf16bits(v);
        }
      }
    }
  }
  __syncthreads();
}

// layer 7: K=256 -> N=32. 8 waves: wave w owns rows (w&3)*16..+16 and the
// 16-col half (w>>2); f32 output scattered to out[tok][32] via perm.
__device__ __forceinline__ void run_layer7(
    const __hip_bfloat16* __restrict__ W7, const float* __restrict__ b7,
    const __hip_bfloat16* __restrict__ inb, float* __restrict__ out,
    const int* __restrict__ perm, int m0, int lane, int wave) {
  constexpr int KL = 256;
  int rseg = wave & 3, jseg = wave >> 2;
  f32x4 acc;
  acc[0] = 0.f; acc[1] = 0.f; acc[2] = 0.f; acc[3] = 0.f;
  const __hip_bfloat16* wbase =
      W7 + (size_t)(jseg * 16 + (lane & 15)) * KL + ((lane >> 4) << 3);
  int ar = rseg * 16 + (lane & 15);
#pragma unroll
  for (int s = 0; s < 4; ++s) {
#pragma unroll
    for (int h = 0; h < 2; ++h) {
      int kbase = s * 64 + h * 32;
      int cj = (kbase >> 3) + (lane >> 4);
      int js = cj ^ (ar & 7);
      s16x8 a = *(const s16x8*)(inb + ar * KL + js * 8);
      s16x8 w = *(const s16x8*)(wbase + kbase);
      acc = __builtin_amdgcn_mfma_f32_16x16x32_bf16(a, w, acc, 0, 0, 0);
    }
  }
  int nc = jseg * 16 + (lane & 15);
  float bv = b7[nc];
#pragma unroll
  for (int r = 0; r < 4; ++r) {
    int mr = rseg * 16 + ((lane >> 4) << 2) + r;
    int tok = perm[m0 + mr];
    if (tok >= 0) out[(size_t)tok * 32 + nc] = acc[r] + bv;
  }
}

__global__ __launch_bounds__(512) void k_fused(
    const __hip_bfloat16* __restrict__ Xs,
    const __hip_bfloat16* __restrict__ W1, const __hip_bfloat16* __restrict__ W2,
    const __hip_bfloat16* __restrict__ W3, const __hip_bfloat16* __restrict__ W4,
    const __hip_bfloat16* __restrict__ W5, const __hip_bfloat16* __restrict__ W6,
    const __hip_bfloat16* __restrict__ W7,
    const float* __restrict__ B1, const float* __restrict__ B2,
    const float* __restrict__ B3, const float* __restrict__ B4,
    const float* __restrict__ B5, const float* __restrict__ B6,
    const float* __restrict__ B7,
    float* __restrict__ out,
    const int* __restrict__ meta, const int* __restrict__ perm) {
  __shared__ __hip_bfloat16 buf0[MROWS * 512];   // 64 KB
  __shared__ __hip_bfloat16 buf1[MROWS * 512];   // 64 KB
  const int* offp = meta + 16;
  int e = blockIdx.x & 7;                     // expert -> XCD affinity
  int s = blockIdx.x >> 3;
  int m0 = offp[e] + s * MROWS;
  if (m0 >= offp[e + 1]) return;
  int tid = threadIdx.x, lane = tid & 63, wave = tid >> 6;

  // stage the 64x128 bf16 input slab (swizzled source, linear LDS dest)
#pragma unroll
  for (int i = 0; i < 2; ++i) {
    int c = i * 512 + tid;
    int r = c >> 4, kc = c & 15;
    int kcs = kc ^ (r & 7);
    gload_lds16(Xs + (size_t)(m0 + r) * 128 + kcs * 8, (char*)buf0 + c * 16);
  }
  asm volatile("s_waitcnt vmcnt(0)" ::: "memory");
  __builtin_amdgcn_s_barrier();

  run_layer<128, 512, true >(W1 + (size_t)e * 512 * 128, B1 + e * 512, buf0, buf1, lane, wave);
  run_layer<512, 512, true >(W2 + (size_t)e * 512 * 512, B2 + e * 512, buf1, buf0, lane, wave);
  run_layer<512, 512, false>(W3 + (size_t)e * 512 * 512, B3 + e * 512, buf0, buf1, lane, wave);
  run_layer<512, 512, true >(W4 + (size_t)e * 512 * 512, B4 + e * 512, buf1, buf0, lane, wave);
  run_layer<512, 512, true >(W5 + (size_t)e * 512 * 512, B5 + e * 512, buf0, buf1, lane, wave);
  run_layer<512, 256, false>(W6 + (size_t)e * 256 * 512, B6 + e * 256, buf1, buf0, lane, wave);
  run_layer7(W7 + (size_t)e * 32 * 256, B7 + e * 32, buf0, out, perm, m0, lane, wave);
}

// ---------------- host ----------------

extern "C" void kernel_launch(void* const* d_in, const int* in_sizes, int n_in,
                              void* d_out, int out_size, void* d_ws, size_t ws_size,
                              hipStream_t stream) {
  const float* input = (const float*)d_in[0];
  const float* Wf[7]; const float* Bf[7];
  for (int i = 0; i < 7; ++i) { Wf[i] = (const float*)d_in[1 + 2 * i]; Bf[i] = (const float*)d_in[2 + 2 * i]; }
  float* out = (float*)d_out;

  static const int NN[7] = {512, 512, 512, 512, 512, 256, 32};
  static const int KK[7] = {128, 512, 512, 512, 512, 512, 256};

  char* ws = (char*)d_ws;
  size_t off = 0;
  auto carve = [&](size_t bytes) {
    void* p = ws + off;
    off = (off + bytes + 255) & ~(size_t)255;
    return p;
  };
  int* meta      = (int*)carve(128);                    // offp at meta[16..24]
  int* ids       = (int*)carve(sizeof(int) * T_TOK);
  int* rowOf     = (int*)carve(sizeof(int) * T_TOK);
  int* perm      = (int*)carve(sizeof(int) * MCAP);
  int* blockHist = (int*)carve(sizeof(int) * NBLK * NEXP);
  int* blockBase = (int*)carve(sizeof(int) * NBLK * NEXP);
  __hip_bfloat16* Xs = (__hip_bfloat16*)carve((size_t)MCAP * 128 * 2);
  __hip_bfloat16* Wb[7];
  for (int i = 0; i < 7; ++i) Wb[i] = (__hip_bfloat16*)carve((size_t)NEXP * NN[i] * KK[i] * 2);

  k_init<<<dim3((MCAP + 255) / 256), 256, 0, stream>>>(perm);
  for (int i = 0; i < 7; ++i) {
    int n4 = NEXP * NN[i] * KK[i] / 4;
    k_w2bf<<<dim3((n4 + 255) / 256), 256, 0, stream>>>(Wf[i], (unsigned long long*)Wb[i], n4);
  }
  k_hist<<<dim3(NBLK), RBLK, 0, stream>>>(input, ids, blockHist);
  k_scan<<<dim3(1), 64, 0, stream>>>(blockHist, blockBase, meta);
  k_assign<<<dim3(NBLK), RBLK, 0, stream>>>(ids, blockBase, rowOf, perm);
  k_gather<<<dim3(T_TOK * 32 / 256), 256, 0, stream>>>(input, rowOf, Xs);
  k_padfill<<<dim3((MCAP + 255) / 256), 256, 0, stream>>>(meta, perm, (unsigned int*)Xs);

  // grid = 8 experts x SLOTS slab slots; inactive slots early-exit.
  // bid&7 = expert -> XCD affinity.
  k_fused<<<dim3(8 * SLOTS), 512, 0, stream>>>(
      Xs, Wb[0], Wb[1], Wb[2], Wb[3], Wb[4], Wb[5], Wb[6],
      Bf[0], Bf[1], Bf[2], Bf[3], Bf[4], Bf[5], Bf[6],
      out, meta, perm);
}

// Round 11
// 281.917 us; speedup vs baseline: 1.1629x; 1.1629x over previous
//
#include <hip/hip_runtime.h>
#include <hip/hip_bf16.h>
#include <stdint.h>

#define T_TOK 32768
#define NEXP 8
#define MROWS 64            // slab rows per block
#define MT64_MAX 520        // 64-row granules incl. per-expert padding (pad=64)
#define MCAP (MT64_MAX * 64)
#define RBLK 512            // routing block threads
#define NBLK (T_TOK / RBLK) // routing blocks = 64
#define SLOTS 128           // slab slots per expert (8192 tokens; >50 sigma)

typedef short s16x8 __attribute__((ext_vector_type(8)));
typedef float f32x4 __attribute__((ext_vector_type(4)));

__device__ __forceinline__ void gload_lds16(const void* g, void* l) {
  typedef const __attribute__((address_space(1))) unsigned int gu32;
  typedef __attribute__((address_space(3))) unsigned int lu32;
  __builtin_amdgcn_global_load_lds((gu32*)(unsigned long long)g,
                                   (lu32*)(unsigned int)(unsigned long long)l,
                                   16, 0, 0);
}

__device__ __forceinline__ unsigned short bf16bits(float v) {
  __hip_bfloat16 h = __float2bfloat16(v);
  return *(unsigned short*)&h;
}

// ---------------- routing (atomic-free at device scope) ----------------

__global__ void k_init(int* __restrict__ perm) {
  int i = blockIdx.x * blockDim.x + threadIdx.x;
  if (i < MCAP) perm[i] = -1;
}

__global__ void k_hist(const float* __restrict__ in, int* __restrict__ ids,
                       int* __restrict__ blockHist) {
  __shared__ int h[NEXP];
  int tid = threadIdx.x;
  if (tid < NEXP) h[tid] = 0;
  __syncthreads();
  int t = blockIdx.x * RBLK + tid;
  const float* p = in + (size_t)t * 136 + 128;
  float bv = p[0]; int best = 0;
#pragma unroll
  for (int j = 1; j < 8; ++j) { float v = p[j]; if (v > bv) { bv = v; best = j; } }
  ids[t] = best;
  atomicAdd(&h[best], 1);   // LDS atomic — cheap
  __syncthreads();
  if (tid < NEXP) blockHist[blockIdx.x * NEXP + tid] = h[tid];
}

// single block: per-expert exclusive prefix over blocks + 64-padded expert offsets
__global__ void k_scan(const int* __restrict__ blockHist, int* __restrict__ blockBase,
                       int* __restrict__ meta) {
  __shared__ int cnt[NEXP];
  int e = threadIdx.x;
  if (e < NEXP) {
    int acc = 0;
    for (int b = 0; b < NBLK; ++b) {
      blockBase[b * NEXP + e] = acc;
      acc += blockHist[b * NEXP + e];
    }
    cnt[e] = acc;
  }
  __syncthreads();
  if (e == 0) {
    int acc = 0;
    for (int i = 0; i < NEXP; ++i) {
      meta[16 + i] = acc;
      acc += ((cnt[i] + 63) / 64) * 64;   // pad to 64-row slabs
    }
    meta[16 + NEXP] = acc;
  }
  __syncthreads();
  if (e < NEXP) {
    int o = meta[16 + e];
    for (int b = 0; b < NBLK; ++b) blockBase[b * NEXP + e] += o;
  }
}

__global__ void k_assign(const int* __restrict__ ids, const int* __restrict__ blockBase,
                         int* __restrict__ rowOf, int* __restrict__ perm) {
  __shared__ int cur[NEXP];
  int tid = threadIdx.x;
  if (tid < NEXP) cur[tid] = blockBase[blockIdx.x * NEXP + tid];
  __syncthreads();
  int t = blockIdx.x * RBLK + tid;
  int e = ids[t];
  int row = atomicAdd(&cur[e], 1);   // LDS atomic — cheap
  rowOf[t] = row;
  perm[row] = t;
}

__global__ void k_gather(const float* __restrict__ in, const int* __restrict__ rowOf,
                         __hip_bfloat16* __restrict__ Xs) {
  int g = blockIdx.x * blockDim.x + threadIdx.x;
  if (g >= T_TOK * 32) return;
  int t = g >> 5, c = g & 31;
  int row = rowOf[t];
  f32x4 v = *(const f32x4*)(in + (size_t)t * 136 + c * 4);
  union { unsigned short u[4]; unsigned long long ll; } pk;
#pragma unroll
  for (int j = 0; j < 4; ++j) pk.u[j] = bf16bits(v[j]);
  *(unsigned long long*)(Xs + (size_t)row * 128 + c * 4) = pk.ll;
}

__global__ void k_padfill(const int* __restrict__ meta, const int* __restrict__ perm,
                          unsigned int* __restrict__ Xs32) {
  int row = blockIdx.x * blockDim.x + threadIdx.x;
  if (row >= MCAP) return;
  int mtotal = meta[16 + NEXP];
  if (row < mtotal && perm[row] < 0) {
    unsigned int* p = Xs32 + (size_t)row * 64;
#pragma unroll 4
    for (int c = 0; c < 64; ++c) p[c] = 0;
  }
}

__global__ void k_w2bf(const float* __restrict__ s, unsigned long long* __restrict__ d, int n4) {
  int i = blockIdx.x * blockDim.x + threadIdx.x;
  if (i >= n4) return;
  f32x4 v = ((const f32x4*)s)[i];
  union { unsigned short u[4]; unsigned long long ll; } pk;
#pragma unroll
  for (int j = 0; j < 4; ++j) pk.u[j] = bf16bits(v[j]);
  d[i] = pk.ll;
}

// ---------------- fused persistent MLP (bounded-pressure K-loop) ----
// Block = 512 threads (8 waves) owns a 64-token slab for ALL 7 layers.
// TWO 64 KB LDS activation buffers ping-pong; per wave, two sequential
// 32-col passes; acc f32x4[4][2]=32 regs + W-dbuf 32.
// ROUND 11 FIX: the K-loop is a REAL loop (#pragma unroll 1). Rounds 6-10
// fully unrolled it -> LLVM hoisted dozens of W global-loads ahead of their
// MFMAs -> register pressure ballooned past the 8-wave 128-VGPR budget ->
// persistent ~90 MB/dispatch scratch spill (WRITE_SIZE excess). A bounded
// loop body caps live W-loads at the explicit 2-step double buffer.
// W[e] streams global->VGPR from XCD-local L2 (bid&7 = e -> XCD affinity).

template <int KL, int NL, bool RELU>
__device__ __forceinline__ void run_layer(
    const __hip_bfloat16* __restrict__ Wl,   // expert's W base, layout [NL][KL]
    const float* __restrict__ bl,            // expert's bias base
    const __hip_bfloat16* __restrict__ inb,  // [64][KL] swizzled
    __hip_bfloat16* __restrict__ outb,       // [64][NL] swizzled
    int lane, int wave) {
  constexpr int NS = KL / 64;                // K-steps (2 or 8, always even)
  constexpr int NPASS = NL / 256;            // 2 (NL=512) or 1 (NL=256)

#pragma unroll 1
  for (int p = 0; p < NPASS; ++p) {
    const int n0p = wave * (NL / 8) + p * 32;

    f32x4 acc[4][2];
#pragma unroll
    for (int i = 0; i < 4; ++i)
#pragma unroll
      for (int j = 0; j < 2; ++j) {
        acc[i][j][0] = 0.f; acc[i][j][1] = 0.f; acc[i][j][2] = 0.f; acc[i][j][3] = 0.f;
      }

    const __hip_bfloat16* wbase =
        Wl + (size_t)(n0p + (lane & 15)) * KL + ((lane >> 4) << 3);

    s16x8 wA[2][2], wB[2][2];
#pragma unroll
    for (int j = 0; j < 2; ++j)
#pragma unroll
      for (int h = 0; h < 2; ++h)
        wA[j][h] = *(const s16x8*)(wbase + j * 16 * KL + h * 32);

    auto step = [&](int s, s16x8 (&wu)[2][2], s16x8 (&wp)[2][2]) {
      if (s + 1 < NS) {        // prefetch next K-step's W before the MFMAs
#pragma unroll
        for (int j = 0; j < 2; ++j)
#pragma unroll
          for (int h = 0; h < 2; ++h)
            wp[j][h] = *(const s16x8*)(wbase + j * 16 * KL + (s + 1) * 64 + h * 32);
      }
#pragma unroll
      for (int h = 0; h < 2; ++h) {
        int cj = s * 8 + h * 4 + (lane >> 4);  // 16B chunk index within row
#pragma unroll
        for (int i = 0; i < 4; ++i) {
          int ar = i * 16 + (lane & 15);
          int js = cj ^ (ar & 7);
          s16x8 a = *(const s16x8*)(inb + ar * KL + js * 8);
#pragma unroll
          for (int j = 0; j < 2; ++j)
            acc[i][j] = __builtin_amdgcn_mfma_f32_16x16x32_bf16(a, wu[j][h], acc[i][j], 0, 0, 0);
        }
      }
    };

    // REAL loop (no unroll): bounded register pressure per iteration.
#pragma unroll 1
    for (int s = 0; s < NS; s += 2) {
      step(s, wA, wB);
      step(s + 1, wB, wA);
    }

    // epilogue: bias + relu, write straight to outb (different LDS buffer)
    unsigned short* y16 = (unsigned short*)outb;
#pragma unroll
    for (int j = 0; j < 2; ++j) {
      int nc = n0p + j * 16 + (lane & 15);
      float bv = bl[nc];
#pragma unroll
      for (int i = 0; i < 4; ++i) {
#pragma unroll
        for (int r = 0; r < 4; ++r) {
          int mr = i * 16 + ((lane >> 4) << 2) + r;
          float v = acc[i][j][r] + bv;
          if (RELU) v = fmaxf(v, 0.f);
          y16[mr * NL + (((nc >> 3) ^ (mr & 7)) << 3) + (nc & 7)] = bf16bits(v);
        }
      }
    }
  }
  __syncthreads();
}

// layer 7: K=256 -> N=32. 8 waves: wave w owns rows (w&3)*16..+16 and the
// 16-col half (w>>2); f32 output scattered to out[tok][32] via perm.
__device__ __forceinline__ void run_layer7(
    const __hip_bfloat16* __restrict__ W7, const float* __restrict__ b7,
    const __hip_bfloat16* __restrict__ inb, float* __restrict__ out,
    const int* __restrict__ perm, int m0, int lane, int wave) {
  constexpr int KL = 256;
  int rseg = wave & 3, jseg = wave >> 2;
  f32x4 acc;
  acc[0] = 0.f; acc[1] = 0.f; acc[2] = 0.f; acc[3] = 0.f;
  const __hip_bfloat16* wbase =
      W7 + (size_t)(jseg * 16 + (lane & 15)) * KL + ((lane >> 4) << 3);
  int ar = rseg * 16 + (lane & 15);
#pragma unroll 1
  for (int s = 0; s < 4; ++s) {
#pragma unroll
    for (int h = 0; h < 2; ++h) {
      int kbase = s * 64 + h * 32;
      int cj = (kbase >> 3) + (lane >> 4);
      int js = cj ^ (ar & 7);
      s16x8 a = *(const s16x8*)(inb + ar * KL + js * 8);
      s16x8 w = *(const s16x8*)(wbase + kbase);
      acc = __builtin_amdgcn_mfma_f32_16x16x32_bf16(a, w, acc, 0, 0, 0);
    }
  }
  int nc = jseg * 16 + (lane & 15);
  float bv = b7[nc];
#pragma unroll
  for (int r = 0; r < 4; ++r) {
    int mr = rseg * 16 + ((lane >> 4) << 2) + r;
    int tok = perm[m0 + mr];
    if (tok >= 0) out[(size_t)tok * 32 + nc] = acc[r] + bv;
  }
}

__global__ __launch_bounds__(512) void k_fused(
    const __hip_bfloat16* __restrict__ Xs,
    const __hip_bfloat16* __restrict__ W1, const __hip_bfloat16* __restrict__ W2,
    const __hip_bfloat16* __restrict__ W3, const __hip_bfloat16* __restrict__ W4,
    const __hip_bfloat16* __restrict__ W5, const __hip_bfloat16* __restrict__ W6,
    const __hip_bfloat16* __restrict__ W7,
    const float* __restrict__ B1, const float* __restrict__ B2,
    const float* __restrict__ B3, const float* __restrict__ B4,
    const float* __restrict__ B5, const float* __restrict__ B6,
    const float* __restrict__ B7,
    float* __restrict__ out,
    const int* __restrict__ meta, const int* __restrict__ perm) {
  __shared__ __hip_bfloat16 buf0[MROWS * 512];   // 64 KB
  __shared__ __hip_bfloat16 buf1[MROWS * 512];   // 64 KB
  const int* offp = meta + 16;
  int e = blockIdx.x & 7;                     // expert -> XCD affinity
  int s = blockIdx.x >> 3;
  int m0 = offp[e] + s * MROWS;
  if (m0 >= offp[e + 1]) return;
  int tid = threadIdx.x, lane = tid & 63, wave = tid >> 6;

  // stage the 64x128 bf16 input slab (swizzled source, linear LDS dest)
#pragma unroll
  for (int i = 0; i < 2; ++i) {
    int c = i * 512 + tid;
    int r = c >> 4, kc = c & 15;
    int kcs = kc ^ (r & 7);
    gload_lds16(Xs + (size_t)(m0 + r) * 128 + kcs * 8, (char*)buf0 + c * 16);
  }
  asm volatile("s_waitcnt vmcnt(0)" ::: "memory");
  __builtin_amdgcn_s_barrier();

  run_layer<128, 512, true >(W1 + (size_t)e * 512 * 128, B1 + e * 512, buf0, buf1, lane, wave);
  run_layer<512, 512, true >(W2 + (size_t)e * 512 * 512, B2 + e * 512, buf1, buf0, lane, wave);
  run_layer<512, 512, false>(W3 + (size_t)e * 512 * 512, B3 + e * 512, buf0, buf1, lane, wave);
  run_layer<512, 512, true >(W4 + (size_t)e * 512 * 512, B4 + e * 512, buf1, buf0, lane, wave);
  run_layer<512, 512, true >(W5 + (size_t)e * 512 * 512, B5 + e * 512, buf0, buf1, lane, wave);
  run_layer<512, 256, false>(W6 + (size_t)e * 256 * 512, B6 + e * 256, buf1, buf0, lane, wave);
  run_layer7(W7 + (size_t)e * 32 * 256, B7 + e * 32, buf0, out, perm, m0, lane, wave);
}

// ---------------- host ----------------

extern "C" void kernel_launch(void* const* d_in, const int* in_sizes, int n_in,
                              void* d_out, int out_size, void* d_ws, size_t ws_size,
                              hipStream_t stream) {
  const float* input = (const float*)d_in[0];
  const float* Wf[7]; const float* Bf[7];
  for (int i = 0; i < 7; ++i) { Wf[i] = (const float*)d_in[1 + 2 * i]; Bf[i] = (const float*)d_in[2 + 2 * i]; }
  float* out = (float*)d_out;

  static const int NN[7] = {512, 512, 512, 512, 512, 256, 32};
  static const int KK[7] = {128, 512, 512, 512, 512, 512, 256};

  char* ws = (char*)d_ws;
  size_t off = 0;
  auto carve = [&](size_t bytes) {
    void* p = ws + off;
    off = (off + bytes + 255) & ~(size_t)255;
    return p;
  };
  int* meta      = (int*)carve(128);                    // offp at meta[16..24]
  int* ids       = (int*)carve(sizeof(int) * T_TOK);
  int* rowOf     = (int*)carve(sizeof(int) * T_TOK);
  int* perm      = (int*)carve(sizeof(int) * MCAP);
  int* blockHist = (int*)carve(sizeof(int) * NBLK * NEXP);
  int* blockBase = (int*)carve(sizeof(int) * NBLK * NEXP);
  __hip_bfloat16* Xs = (__hip_bfloat16*)carve((size_t)MCAP * 128 * 2);
  __hip_bfloat16* Wb[7];
  for (int i = 0; i < 7; ++i) Wb[i] = (__hip_bfloat16*)carve((size_t)NEXP * NN[i] * KK[i] * 2);

  k_init<<<dim3((MCAP + 255) / 256), 256, 0, stream>>>(perm);
  for (int i = 0; i < 7; ++i) {
    int n4 = NEXP * NN[i] * KK[i] / 4;
    k_w2bf<<<dim3((n4 + 255) / 256), 256, 0, stream>>>(Wf[i], (unsigned long long*)Wb[i], n4);
  }
  k_hist<<<dim3(NBLK), RBLK, 0, stream>>>(input, ids, blockHist);
  k_scan<<<dim3(1), 64, 0, stream>>>(blockHist, blockBase, meta);
  k_assign<<<dim3(NBLK), RBLK, 0, stream>>>(ids, blockBase, rowOf, perm);
  k_gather<<<dim3(T_TOK * 32 / 256), 256, 0, stream>>>(input, rowOf, Xs);
  k_padfill<<<dim3((MCAP + 255) / 256), 256, 0, stream>>>(meta, perm, (unsigned int*)Xs);

  // grid = 8 experts x SLOTS slab slots; inactive slots early-exit.
  // bid&7 = expert -> XCD affinity.
  k_fused<<<dim3(8 * SLOTS), 512, 0, stream>>>(
      Xs, Wb[0], Wb[1], Wb[2], Wb[3], Wb[4], Wb[5], Wb[6],
      Bf[0], Bf[1], Bf[2], Bf[3], Bf[4], Bf[5], Bf[6],
      out, meta, perm);
}

// Round 12
// 278.743 us; speedup vs baseline: 1.1761x; 1.0114x over previous
//
#include <hip/hip_runtime.h>
#include <hip/hip_bf16.h>
#include <stdint.h>

#define T_TOK 32768
#define NEXP 8
#define MROWS 64            // slab rows per block
#define MT64_MAX 520        // 64-row granules incl. per-expert padding (pad=64)
#define MCAP (MT64_MAX * 64)
#define RBLK 512            // routing block threads
#define NBLK (T_TOK / RBLK) // routing blocks = 64
#define SLOTS 128           // slab slots per expert (8192 tokens; >50 sigma)

typedef short s16x8 __attribute__((ext_vector_type(8)));
typedef float f32x4 __attribute__((ext_vector_type(4)));

__device__ __forceinline__ void gload_lds16(const void* g, void* l) {
  typedef const __attribute__((address_space(1))) unsigned int gu32;
  typedef __attribute__((address_space(3))) unsigned int lu32;
  __builtin_amdgcn_global_load_lds((gu32*)(unsigned long long)g,
                                   (lu32*)(unsigned int)(unsigned long long)l,
                                   16, 0, 0);
}

__device__ __forceinline__ unsigned short bf16bits(float v) {
  __hip_bfloat16 h = __float2bfloat16(v);
  return *(unsigned short*)&h;
}

__device__ __forceinline__ unsigned int pack2bf(float a, float b) {
  union { __hip_bfloat16 h[2]; unsigned int u; } p;
  p.h[0] = __float2bfloat16(a);
  p.h[1] = __float2bfloat16(b);
  return p.u;
}

// ---------------- routing (atomic-free at device scope) ----------------

__global__ void k_init(int* __restrict__ perm) {
  int i = blockIdx.x * blockDim.x + threadIdx.x;
  if (i < MCAP) perm[i] = -1;
}

__global__ void k_hist(const float* __restrict__ in, int* __restrict__ ids,
                       int* __restrict__ blockHist) {
  __shared__ int h[NEXP];
  int tid = threadIdx.x;
  if (tid < NEXP) h[tid] = 0;
  __syncthreads();
  int t = blockIdx.x * RBLK + tid;
  const float* p = in + (size_t)t * 136 + 128;
  float bv = p[0]; int best = 0;
#pragma unroll
  for (int j = 1; j < 8; ++j) { float v = p[j]; if (v > bv) { bv = v; best = j; } }
  ids[t] = best;
  atomicAdd(&h[best], 1);   // LDS atomic — cheap
  __syncthreads();
  if (tid < NEXP) blockHist[blockIdx.x * NEXP + tid] = h[tid];
}

// single block: per-expert exclusive prefix over blocks + 64-padded expert offsets
__global__ void k_scan(const int* __restrict__ blockHist, int* __restrict__ blockBase,
                       int* __restrict__ meta) {
  __shared__ int cnt[NEXP];
  int e = threadIdx.x;
  if (e < NEXP) {
    int acc = 0;
    for (int b = 0; b < NBLK; ++b) {
      blockBase[b * NEXP + e] = acc;
      acc += blockHist[b * NEXP + e];
    }
    cnt[e] = acc;
  }
  __syncthreads();
  if (e == 0) {
    int acc = 0;
    for (int i = 0; i < NEXP; ++i) {
      meta[16 + i] = acc;
      acc += ((cnt[i] + 63) / 64) * 64;   // pad to 64-row slabs
    }
    meta[16 + NEXP] = acc;
  }
  __syncthreads();
  if (e < NEXP) {
    int o = meta[16 + e];
    for (int b = 0; b < NBLK; ++b) blockBase[b * NEXP + e] += o;
  }
}

__global__ void k_assign(const int* __restrict__ ids, const int* __restrict__ blockBase,
                         int* __restrict__ rowOf, int* __restrict__ perm) {
  __shared__ int cur[NEXP];
  int tid = threadIdx.x;
  if (tid < NEXP) cur[tid] = blockBase[blockIdx.x * NEXP + tid];
  __syncthreads();
  int t = blockIdx.x * RBLK + tid;
  int e = ids[t];
  int row = atomicAdd(&cur[e], 1);   // LDS atomic — cheap
  rowOf[t] = row;
  perm[row] = t;
}

__global__ void k_gather(const float* __restrict__ in, const int* __restrict__ rowOf,
                         __hip_bfloat16* __restrict__ Xs) {
  int g = blockIdx.x * blockDim.x + threadIdx.x;
  if (g >= T_TOK * 32) return;
  int t = g >> 5, c = g & 31;
  int row = rowOf[t];
  f32x4 v = *(const f32x4*)(in + (size_t)t * 136 + c * 4);
  union { unsigned short u[4]; unsigned long long ll; } pk;
#pragma unroll
  for (int j = 0; j < 4; ++j) pk.u[j] = bf16bits(v[j]);
  *(unsigned long long*)(Xs + (size_t)row * 128 + c * 4) = pk.ll;
}

__global__ void k_padfill(const int* __restrict__ meta, const int* __restrict__ perm,
                          unsigned int* __restrict__ Xs32) {
  int row = blockIdx.x * blockDim.x + threadIdx.x;
  if (row >= MCAP) return;
  int mtotal = meta[16 + NEXP];
  if (row < mtotal && perm[row] < 0) {
    unsigned int* p = Xs32 + (size_t)row * 64;
#pragma unroll 4
    for (int c = 0; c < 64; ++c) p[c] = 0;
  }
}

__global__ void k_w2bf(const float* __restrict__ s, unsigned long long* __restrict__ d, int n4) {
  int i = blockIdx.x * blockDim.x + threadIdx.x;
  if (i >= n4) return;
  f32x4 v = ((const f32x4*)s)[i];
  union { unsigned short u[4]; unsigned long long ll; } pk;
#pragma unroll
  for (int j = 0; j < 4; ++j) pk.u[j] = bf16bits(v[j]);
  d[i] = pk.ll;
}

// ---------------- fused persistent MLP (16 waves, swapped-operand MFMA) ----
// Block = 1024 threads (16 waves, 4/SIMD — round-11 was 2/SIMD and pure
// latency-bound) owns a 64-token slab for ALL 7 layers. TWO 64 KB LDS
// activation buffers ping-pong. Per wave: 32 output cols, single pass.
// MFMA operands are SWAPPED: mfma(W_frag, act_frag) -> C has col=token,
// row=outcol, so each lane holds 4 CONSECUTIVE outcols of one token ->
// epilogue is 8 aligned b64 LDS writes per wave (round-11: 64 scattered
// b16 writes = bank-conflict storm, SQ_LDS_BANK_CONFLICT 9.9M).
// K-loop stays a REAL loop (#pragma unroll 1) — full unroll re-creates the
// r6-r10 scratch spill. W[e] streams from XCD-local L2 (bid&7 -> XCD).

template <int KL, int NL, bool RELU>
__device__ __forceinline__ void run_layer(
    const __hip_bfloat16* __restrict__ Wl,   // expert's W base, layout [NL][KL]
    const float* __restrict__ bl,            // expert's bias base
    const __hip_bfloat16* __restrict__ inb,  // [64][KL] swizzled
    __hip_bfloat16* __restrict__ outb,       // [64][NL] swizzled
    int lane, int wave) {
  constexpr int NS = KL / 64;                // K-steps (2 or 8, always even)
  constexpr int WCOLS = NL / 16;             // 32 (NL=512) or 16 (NL=256)
  constexpr int JM = WCOLS / 16;             // 2 or 1
  const int n0w = wave * WCOLS;

  f32x4 acc[JM][4];
#pragma unroll
  for (int jm = 0; jm < JM; ++jm)
#pragma unroll
    for (int it = 0; it < 4; ++it) {
      acc[jm][it][0] = 0.f; acc[jm][it][1] = 0.f; acc[jm][it][2] = 0.f; acc[jm][it][3] = 0.f;
    }

  const __hip_bfloat16* wbase =
      Wl + (size_t)(n0w + (lane & 15)) * KL + ((lane >> 4) << 3);

  s16x8 wA[JM][2], wB[JM][2];
#pragma unroll
  for (int jm = 0; jm < JM; ++jm)
#pragma unroll
    for (int h = 0; h < 2; ++h)
      wA[jm][h] = *(const s16x8*)(wbase + jm * 16 * KL + h * 32);

  auto step = [&](int s, s16x8 (&wu)[JM][2], s16x8 (&wp)[JM][2]) {
    if (s + 1 < NS) {          // prefetch next K-step's W before the MFMAs
#pragma unroll
      for (int jm = 0; jm < JM; ++jm)
#pragma unroll
        for (int h = 0; h < 2; ++h)
          wp[jm][h] = *(const s16x8*)(wbase + jm * 16 * KL + (s + 1) * 64 + h * 32);
    }
#pragma unroll
    for (int h = 0; h < 2; ++h) {
      int cj = s * 8 + h * 4 + (lane >> 4);  // 16B chunk index within row
#pragma unroll
      for (int it = 0; it < 4; ++it) {
        int ar = it * 16 + (lane & 15);      // token row
        int js = cj ^ (ar & 7);
        s16x8 a = *(const s16x8*)(inb + ar * KL + js * 8);
#pragma unroll
        for (int jm = 0; jm < JM; ++jm)
          acc[jm][it] = __builtin_amdgcn_mfma_f32_16x16x32_bf16(wu[jm][h], a, acc[jm][it], 0, 0, 0);
      }
    }
  };

  // REAL loop (no unroll): bounded register pressure per iteration.
#pragma unroll 1
  for (int s = 0; s < NS; s += 2) {
    step(s, wA, wB);
    step(s + 1, wB, wA);
  }

  // epilogue: lane holds 4 consecutive outcols of one token per acc frag
#pragma unroll
  for (int jm = 0; jm < JM; ++jm) {
    int nc0 = n0w + jm * 16 + ((lane >> 4) << 2);   // first of 4 outcols
    f32x4 bv = *(const f32x4*)(bl + nc0);
#pragma unroll
    for (int it = 0; it < 4; ++it) {
      int tl = it * 16 + (lane & 15);               // token row
      float v0 = acc[jm][it][0] + bv[0], v1 = acc[jm][it][1] + bv[1];
      float v2 = acc[jm][it][2] + bv[2], v3 = acc[jm][it][3] + bv[3];
      if (RELU) {
        v0 = fmaxf(v0, 0.f); v1 = fmaxf(v1, 0.f);
        v2 = fmaxf(v2, 0.f); v3 = fmaxf(v3, 0.f);
      }
      unsigned long long u = (unsigned long long)pack2bf(v0, v1) |
                             ((unsigned long long)pack2bf(v2, v3) << 32);
      int elem = tl * NL + (((nc0 >> 3) ^ (tl & 7)) << 3) + (nc0 & 7);
      *(unsigned long long*)(outb + elem) = u;      // 8B aligned
    }
  }
  __syncthreads();
}

// layer 7: K=256 -> N=32 over 64 tokens. Waves 0-7 each own one 16x16 tile
// (it=w&3 token tile, jm=w>>2 col half); waves 8-15 idle (no barrier after).
// Swapped layout -> lane stores 4 consecutive f32 outs = one dwordx4.
__device__ __forceinline__ void run_layer7(
    const __hip_bfloat16* __restrict__ W7, const float* __restrict__ b7,
    const __hip_bfloat16* __restrict__ inb, float* __restrict__ out,
    const int* __restrict__ perm, int m0, int lane, int wave) {
  if (wave >= 8) return;
  constexpr int KL = 256;
  int it = wave & 3, jm = wave >> 2;
  f32x4 acc;
  acc[0] = 0.f; acc[1] = 0.f; acc[2] = 0.f; acc[3] = 0.f;
  const __hip_bfloat16* wbase =
      W7 + (size_t)(jm * 16 + (lane & 15)) * KL + ((lane >> 4) << 3);
  int ar = it * 16 + (lane & 15);
#pragma unroll 1
  for (int s = 0; s < 4; ++s) {
#pragma unroll
    for (int h = 0; h < 2; ++h) {
      int kbase = s * 64 + h * 32;
      int cj = (kbase >> 3) + (lane >> 4);
      int js = cj ^ (ar & 7);
      s16x8 a = *(const s16x8*)(inb + ar * KL + js * 8);
      s16x8 w = *(const s16x8*)(wbase + kbase);
      acc = __builtin_amdgcn_mfma_f32_16x16x32_bf16(w, a, acc, 0, 0, 0);
    }
  }
  int tl = it * 16 + (lane & 15);
  int nc0 = jm * 16 + ((lane >> 4) << 2);
  int tok = perm[m0 + tl];
  if (tok >= 0) {
    f32x4 bv = *(const f32x4*)(b7 + nc0);
    f32x4 r;
    r[0] = acc[0] + bv[0]; r[1] = acc[1] + bv[1];
    r[2] = acc[2] + bv[2]; r[3] = acc[3] + bv[3];
    *(f32x4*)(out + (size_t)tok * 32 + nc0) = r;    // 16B aligned
  }
}

__global__ __launch_bounds__(1024) void k_fused(
    const __hip_bfloat16* __restrict__ Xs,
    const __hip_bfloat16* __restrict__ W1, const __hip_bfloat16* __restrict__ W2,
    const __hip_bfloat16* __restrict__ W3, const __hip_bfloat16* __restrict__ W4,
    const __hip_bfloat16* __restrict__ W5, const __hip_bfloat16* __restrict__ W6,
    const __hip_bfloat16* __restrict__ W7,
    const float* __restrict__ B1, const float* __restrict__ B2,
    const float* __restrict__ B3, const float* __restrict__ B4,
    const float* __restrict__ B5, const float* __restrict__ B6,
    const float* __restrict__ B7,
    float* __restrict__ out,
    const int* __restrict__ meta, const int* __restrict__ perm) {
  __shared__ __hip_bfloat16 buf0[MROWS * 512];   // 64 KB
  __shared__ __hip_bfloat16 buf1[MROWS * 512];   // 64 KB
  const int* offp = meta + 16;
  int e = blockIdx.x & 7;                     // expert -> XCD affinity
  int s = blockIdx.x >> 3;
  int m0 = offp[e] + s * MROWS;
  if (m0 >= offp[e + 1]) return;
  int tid = threadIdx.x, lane = tid & 63, wave = tid >> 6;

  // stage the 64x128 bf16 input slab (swizzled source, linear LDS dest)
#pragma unroll
  for (int i = 0; i < 2; ++i) {
    int c = i * 1024 + tid;
    int r = c >> 4, kc = c & 15;
    int kcs = kc ^ (r & 7);
    gload_lds16(Xs + (size_t)(m0 + r) * 128 + kcs * 8, (char*)buf0 + c * 16);
  }
  asm volatile("s_waitcnt vmcnt(0)" ::: "memory");
  __builtin_amdgcn_s_barrier();

  run_layer<128, 512, true >(W1 + (size_t)e * 512 * 128, B1 + e * 512, buf0, buf1, lane, wave);
  run_layer<512, 512, true >(W2 + (size_t)e * 512 * 512, B2 + e * 512, buf1, buf0, lane, wave);
  run_layer<512, 512, false>(W3 + (size_t)e * 512 * 512, B3 + e * 512, buf0, buf1, lane, wave);
  run_layer<512, 512, true >(W4 + (size_t)e * 512 * 512, B4 + e * 512, buf1, buf0, lane, wave);
  run_layer<512, 512, true >(W5 + (size_t)e * 512 * 512, B5 + e * 512, buf0, buf1, lane, wave);
  run_layer<512, 256, false>(W6 + (size_t)e * 256 * 512, B6 + e * 256, buf1, buf0, lane, wave);
  run_layer7(W7 + (size_t)e * 32 * 256, B7 + e * 32, buf0, out, perm, m0, lane, wave);
}

// ---------------- host ----------------

extern "C" void kernel_launch(void* const* d_in, const int* in_sizes, int n_in,
                              void* d_out, int out_size, void* d_ws, size_t ws_size,
                              hipStream_t stream) {
  const float* input = (const float*)d_in[0];
  const float* Wf[7]; const float* Bf[7];
  for (int i = 0; i < 7; ++i) { Wf[i] = (const float*)d_in[1 + 2 * i]; Bf[i] = (const float*)d_in[2 + 2 * i]; }
  float* out = (float*)d_out;

  static const int NN[7] = {512, 512, 512, 512, 512, 256, 32};
  static const int KK[7] = {128, 512, 512, 512, 512, 512, 256};

  char* ws = (char*)d_ws;
  size_t off = 0;
  auto carve = [&](size_t bytes) {
    void* p = ws + off;
    off = (off + bytes + 255) & ~(size_t)255;
    return p;
  };
  int* meta      = (int*)carve(128);                    // offp at meta[16..24]
  int* ids       = (int*)carve(sizeof(int) * T_TOK);
  int* rowOf     = (int*)carve(sizeof(int) * T_TOK);
  int* perm      = (int*)carve(sizeof(int) * MCAP);
  int* blockHist = (int*)carve(sizeof(int) * NBLK * NEXP);
  int* blockBase = (int*)carve(sizeof(int) * NBLK * NEXP);
  __hip_bfloat16* Xs = (__hip_bfloat16*)carve((size_t)MCAP * 128 * 2);
  __hip_bfloat16* Wb[7];
  for (int i = 0; i < 7; ++i) Wb[i] = (__hip_bfloat16*)carve((size_t)NEXP * NN[i] * KK[i] * 2);

  k_init<<<dim3((MCAP + 255) / 256), 256, 0, stream>>>(perm);
  for (int i = 0; i < 7; ++i) {
    int n4 = NEXP * NN[i] * KK[i] / 4;
    k_w2bf<<<dim3((n4 + 255) / 256), 256, 0, stream>>>(Wf[i], (unsigned long long*)Wb[i], n4);
  }
  k_hist<<<dim3(NBLK), RBLK, 0, stream>>>(input, ids, blockHist);
  k_scan<<<dim3(1), 64, 0, stream>>>(blockHist, blockBase, meta);
  k_assign<<<dim3(NBLK), RBLK, 0, stream>>>(ids, blockBase, rowOf, perm);
  k_gather<<<dim3(T_TOK * 32 / 256), 256, 0, stream>>>(input, rowOf, Xs);
  k_padfill<<<dim3((MCAP + 255) / 256), 256, 0, stream>>>(meta, perm, (unsigned int*)Xs);

  // grid = 8 experts x SLOTS slab slots; inactive slots early-exit.
  // bid&7 = expert -> XCD affinity.
  k_fused<<<dim3(8 * SLOTS), 1024, 0, stream>>>(
      Xs, Wb[0], Wb[1], Wb[2], Wb[3], Wb[4], Wb[5], Wb[6],
      Bf[0], Bf[1], Bf[2], Bf[3], Bf[4], Bf[5], Bf[6],
      out, meta, perm);
}